// Round 6
// baseline (757.322 us; speedup 1.0000x reference)
//
#include <hip/hip_runtime.h>
#include <hip/hip_fp16.h>
#include <math.h>

#define NLEV 16
#define TBLN (1u << 19)
#define TMASK (TBLN - 1u)
#define NPT 4   // points batched per thread in level kernels
#define PR1 2654435761u
#define PR2 805459861u

typedef float f32x4 __attribute__((ext_vector_type(4)));
typedef unsigned int u32;
typedef unsigned int u32x2 __attribute__((ext_vector_type(2)));
typedef unsigned int u32x4 __attribute__((ext_vector_type(4)));

struct ScaleArgs { float s[NLEV]; };

static __device__ __forceinline__ u32 packf2(float a, float b) {
    __half2 h = __floats2half2_rn(a, b);          // low16 = a, high16 = b
    return __builtin_bit_cast(u32, h);
}
static __device__ __forceinline__ float2 unpack16(u32 u) {
    __half2 h = __builtin_bit_cast(__half2, u);
    return __half22float2(h);                      // .x = low half
}
// runtime 4-way select from a u32x4 without memory (cndmask chain, no scratch)
static __device__ __forceinline__ u32 sel4(u32x4 P, u32 idx) {
    u32 s0 = (idx & 1u) ? P.y : P.x;
    u32 s1 = (idx & 1u) ? P.w : P.z;
    return (idx & 2u) ? s1 : s0;
}

// W (f32 [L][T][2]) -> packed fp16 pairs [L][T] (one u32 per table entry)
__global__ __launch_bounds__(256)
void convert_w(const float* __restrict__ W, u32* __restrict__ Wh, int np4)
{
    int i = blockIdx.x * blockDim.x + threadIdx.x;
    if (i >= np4) return;
    const f32x4* src = reinterpret_cast<const f32x4*>(W) + (size_t)i * 2;
    f32x4 A = __builtin_nontemporal_load(src);
    f32x4 B = __builtin_nontemporal_load(src + 1);
    u32x4 o = { packf2(A.x, A.y), packf2(A.z, A.w),
                packf2(B.x, B.y), packf2(B.z, B.w) };
    __builtin_nontemporal_store(o, reinterpret_cast<u32x4*>(Wh) + i);
}

// One kernel per level; table L2-resident. Request-count trick: x-dim prime
// is 1, so entries for x-coords in an aligned-4 group share one aligned 16B
// chunk. Corners (ix, ix+1) are both in chunk (h&~3) whenever ix%4 != 3
// (75%): one dwordx4 covers both -> 4 L2 requests/pt; ix%4==3 -> 8.
// Avg 5 req/pt vs 6 (u32x2 pairing) vs 8 (naive). We are pinned at the L2
// request-rate ceiling (~307 G req/s = 8 XCD x 16 chan x 2.4GHz), so time
// scales directly with request count.
__global__ __launch_bounds__(256)
void level_kernel(const float* __restrict__ x, const u32* __restrict__ Wl,
                  u32* __restrict__ sc, float scale, int N, int TOT)
{
    int t = blockIdx.x * blockDim.x + threadIdx.x;
    if (t >= TOT) return;

    int nn[NPT];
    float dx[NPT], dy[NPT], dz[NPT];
    u32 a0[NPT], a1[NPT], a2[NPT];
    u32x4 P[NPT][4];
    u32 il[NPT][4], ih[NPT][4];   // selection indices into P

    // phase 1: x loads (NT: streamed, don't evict table from L2)
    #pragma unroll
    for (int i = 0; i < NPT; ++i) {
        int n = t + i * TOT;
        if (n > N - 1) n = N - 1;          // duplicate write of same value: benign
        nn[i] = n;
        float px = __builtin_nontemporal_load(&x[(size_t)n * 3 + 0]);
        float py = __builtin_nontemporal_load(&x[(size_t)n * 3 + 1]);
        float pz = __builtin_nontemporal_load(&x[(size_t)n * 3 + 2]);
        float ux = px * scale, uy = py * scale, uz = pz * scale;
        int ix = (int)ux, iy = (int)uy, iz = (int)uz;   // trunc == floor (x>=0)
        dx[i] = ux - (float)ix;
        dy[i] = uy - (float)iy;
        dz[i] = uz - (float)iz;
        a0[i] = (unsigned)ix;
        a1[i] = (unsigned)iy * PR1;
        a2[i] = (unsigned)iz * PR2;
    }

    // phase 2: issue gathers (regular loads -> cached in L2)
    #pragma unroll
    for (int i = 0; i < NPT; ++i) {
        u32 b0 = a0[i] + 1u, b1 = a1[i] + PR1, b2 = a2[i] + PR2;
        u32 E[4] = { a1[i] ^ a2[i], b1 ^ a2[i], a1[i] ^ b2, b1 ^ b2 };
        bool blk = (a0[i] & 3u) != 3u;     // both corners in one 16B chunk
        #pragma unroll
        for (int j = 0; j < 4; ++j) {
            u32 hl = (E[j] ^ a0[i]) & TMASK;
            u32 hh = (E[j] ^ b0) & TMASK;
            if (blk) {
                P[i][j] = *reinterpret_cast<const u32x4*>(Wl + (hl & ~3u));
                il[i][j] = hl & 3u;
                ih[i][j] = hh & 3u;
            } else {
                P[i][j].x = Wl[hl];
                P[i][j].y = Wl[hh];
                il[i][j] = 0u;
                ih[i][j] = 1u;
            }
        }
    }

    // phase 3: select + trilinear reduce (reference fold order), NT store
    #pragma unroll
    for (int i = 0; i < NPT; ++i) {
        float ax = 0.f, ay = 0.f;
        #pragma unroll
        for (int j = 0; j < 4; ++j) {
            // corner v=2j (x=ix): weight wx = 1-dx ; corner v=2j+1: wx = dx
            float wy = (j & 1) ? dy[i] : 1.f - dy[i];
            float wz = (j & 2) ? dz[i] : 1.f - dz[i];
            float wyz = wy * wz;
            float2 flo = unpack16(sel4(P[i][j], il[i][j]));
            float2 fhi = unpack16(sel4(P[i][j], ih[i][j]));
            float wlo = (1.f - dx[i]) * wyz;
            float whi = dx[i] * wyz;
            ax = fmaf(flo.x, wlo, ax);
            ay = fmaf(flo.y, wlo, ay);
            ax = fmaf(fhi.x, whi, ax);
            ay = fmaf(fhi.y, whi, ay);
        }
        __builtin_nontemporal_store(packf2(ax, ay), sc + nn[i]);
    }
}

// Assemble 128B output rows from fp16 scratch [l][n] -> out [n][32] f32.
__global__ __launch_bounds__(256)
void transpose_kernel(const u32* __restrict__ sc, float* __restrict__ out, int N)
{
    int n = blockIdx.x * blockDim.x + threadIdx.x;
    if (n >= N) return;
    float r[2 * NLEV];
    #pragma unroll
    for (int l = 0; l < NLEV; ++l) {
        u32 u = __builtin_nontemporal_load(sc + (size_t)l * N + n);
        float2 f = unpack16(u);
        r[2 * l + 0] = f.x;
        r[2 * l + 1] = f.y;
    }
    f32x4* o = reinterpret_cast<f32x4*>(out + (size_t)n * (2 * NLEV));
    #pragma unroll
    for (int j = 0; j < 8; ++j) {
        f32x4 v = { r[4 * j + 0], r[4 * j + 1], r[4 * j + 2], r[4 * j + 3] };
        o[j] = v;   // regular store: L2 merges 16B pieces into full lines
    }
}

// ---------------- fallback (round-1 kernel, known-good, f32 exact) ----------
__global__ __launch_bounds__(256)
void hashenc_fallback(const float* __restrict__ x, const float* __restrict__ W,
                      float* __restrict__ out, ScaleArgs sc, int N)
{
    int n = blockIdx.x * blockDim.x + threadIdx.x;
    if (n >= N) return;
    float px = x[(size_t)n * 3 + 0];
    float py = x[(size_t)n * 3 + 1];
    float pz = x[(size_t)n * 3 + 2];
    float acc[2 * NLEV];
    #pragma unroll
    for (int l = 0; l < NLEV; ++l) {
        float s = sc.s[l];
        float ux = px * s, uy = py * s, uz = pz * s;
        int ix = (int)ux, iy = (int)uy, iz = (int)uz;
        float dx = ux - (float)ix, dy = uy - (float)iy, dz = uz - (float)iz;
        unsigned a0 = (unsigned)ix;
        unsigned a1 = (unsigned)iy * PR1;
        unsigned a2 = (unsigned)iz * PR2;
        unsigned b0 = a0 + 1u, b1 = a1 + PR1, b2 = a2 + PR2;
        const float* Wl = W + (size_t)l * TBLN * 2u;
        float ax = 0.f, ay = 0.f;
        #pragma unroll
        for (int v = 0; v < 8; ++v) {
            unsigned h = ((v & 1) ? b0 : a0) ^ ((v & 2) ? b1 : a1) ^ ((v & 4) ? b2 : a2);
            h &= TMASK;
            float wx = (v & 1) ? dx : 1.f - dx;
            float wy = (v & 2) ? dy : 1.f - dy;
            float wz = (v & 4) ? dz : 1.f - dz;
            float w = (wx * wy) * wz;
            const float2 fvv = *reinterpret_cast<const float2*>(Wl + (size_t)h * 2u);
            ax = fmaf(fvv.x, w, ax);
            ay = fmaf(fvv.y, w, ay);
        }
        acc[2 * l + 0] = ax;
        acc[2 * l + 1] = ay;
    }
    float4* o = reinterpret_cast<float4*>(out + (size_t)n * (2 * NLEV));
    #pragma unroll
    for (int j = 0; j < 8; ++j)
        o[j] = make_float4(acc[4 * j + 0], acc[4 * j + 1], acc[4 * j + 2], acc[4 * j + 3]);
}

extern "C" void kernel_launch(void* const* d_in, const int* in_sizes, int n_in,
                              void* d_out, int out_size, void* d_ws, size_t ws_size,
                              hipStream_t stream) {
    const float* x = (const float*)d_in[0];
    const float* W = (const float*)d_in[1];
    float* out = (float*)d_out;
    int N = in_sizes[0] / 3;

    // numpy-exact scales: b = exp((log(2048)-log(16))/16); s_l = float32(16*b**l)
    ScaleArgs sc;
    double b = exp((log(2048.0) - log(16.0)) / 16.0);
    for (int l = 0; l < NLEV; ++l) {
        double p;
        switch (l) {
            case 0: p = 1.0; break;
            case 1: p = b;   break;
            case 2: p = b * b; break;
            default: p = pow(b, (double)l); break;
        }
        sc.s[l] = (float)(16.0 * p);
    }

    size_t whalf_u32 = (size_t)NLEV * TBLN;                 // 33.5MB
    size_t scratch_u32 = (size_t)NLEV * (size_t)N;          // 128MB
    size_t need = (whalf_u32 + scratch_u32) * sizeof(u32);

    if (ws_size >= need) {
        u32* Wh = (u32*)d_ws;
        u32* scratch = Wh + whalf_u32;

        int np4 = (int)(whalf_u32 / 4);
        hipLaunchKernelGGL(convert_w, dim3((np4 + 255) / 256), dim3(256), 0, stream,
                           W, Wh, np4);

        int TOT = (N + NPT - 1) / NPT;
        int gl = (TOT + 255) / 256;
        for (int l = 0; l < NLEV; ++l) {
            hipLaunchKernelGGL(level_kernel, dim3(gl), dim3(256), 0, stream,
                               x, Wh + (size_t)l * TBLN,
                               scratch + (size_t)l * (size_t)N,
                               sc.s[l], N, TOT);
        }
        int gt = (N + 255) / 256;
        hipLaunchKernelGGL(transpose_kernel, dim3(gt), dim3(256), 0, stream,
                           scratch, out, N);
    } else {
        int grid = (N + 255) / 256;
        hipLaunchKernelGGL(hashenc_fallback, dim3(grid), dim3(256), 0, stream,
                           x, W, out, sc, N);
    }
}

// Round 7
// 736.142 us; speedup vs baseline: 1.0288x; 1.0288x over previous
//
#include <hip/hip_runtime.h>
#include <hip/hip_fp16.h>
#include <math.h>

#define NLEV 16
#define NDENSE 6          // levels 0..5 use dense pair-duplicated grids
#define TBLN (1u << 19)
#define TMASK (TBLN - 1u)
#define NPT 4             // points batched per thread in level kernels
#define PR1 2654435761u
#define PR2 805459861u

typedef float f32x4 __attribute__((ext_vector_type(4)));
typedef unsigned int u32;
typedef unsigned int u32x2 __attribute__((ext_vector_type(2)));
typedef unsigned int u32x4 __attribute__((ext_vector_type(4)));

struct ScaleArgs { float s[NLEV]; };

static __device__ __forceinline__ u32 packf2(float a, float b) {
    __half2 h = __floats2half2_rn(a, b);          // low16 = a, high16 = b
    return __builtin_bit_cast(u32, h);
}
static __device__ __forceinline__ float2 unpack16(u32 u) {
    __half2 h = __builtin_bit_cast(__half2, u);
    return __half22float2(h);                      // .x = low half
}

// W (f32 [L][T][2]) -> packed fp16 pairs [L][T] (one u32 per table entry)
__global__ __launch_bounds__(256)
void convert_w(const float* __restrict__ W, u32* __restrict__ Wh, int np4)
{
    int i = blockIdx.x * blockDim.x + threadIdx.x;
    if (i >= np4) return;
    const f32x4* src = reinterpret_cast<const f32x4*>(W) + (size_t)i * 2;
    f32x4 A = __builtin_nontemporal_load(src);
    f32x4 B = __builtin_nontemporal_load(src + 1);
    u32x4 o = { packf2(A.x, A.y), packf2(A.z, A.w),
                packf2(B.x, B.y), packf2(B.z, B.w) };
    __builtin_nontemporal_store(o, reinterpret_cast<u32x4*>(Wh) + i);
}

// Dense pair-duplicated grid for one coarse level:
// Gp[(iz*D + iy)*(D-1) + ix] = ( Wh[h(ix,iy,iz)], Wh[h(ix+1,iy,iz)] ).
// Bit-copies of the fp16 table -> results identical to hash path.
__global__ __launch_bounds__(256)
void build_dense(const u32* __restrict__ Wl, u32x2* __restrict__ Gp, int D, int P)
{
    int v = blockIdx.x * blockDim.x + threadIdx.x;
    if (v >= P) return;
    int Dx = D - 1;
    int ix = v % Dx;
    int rest = v / Dx;
    int iy = rest % D;
    int iz = rest / D;
    u32 e = ((u32)iy * PR1) ^ ((u32)iz * PR2);
    u32 h0 = (e ^ (u32)ix) & TMASK;
    u32 h1 = (e ^ (u32)(ix + 1)) & TMASK;
    u32x2 o = { Wl[h0], Wl[h1] };
    Gp[v] = o;
}

// Coarse-level kernel: exactly 4 aligned 8B gathers per point (the 4 (y,z)
// corner pairs), each pair covering both x-corners. We are pinned at the L2
// request-rate ceiling (~310 G 8B-req/s), so 4 req/pt beats the hash path's
// 6 avg.
__global__ __launch_bounds__(256)
void level_dense(const float* __restrict__ x, const u32x2* __restrict__ Gp,
                 u32* __restrict__ sc, float scale, int D, int N, int TOT)
{
    int t = blockIdx.x * blockDim.x + threadIdx.x;
    if (t >= TOT) return;
    const int Dx = D - 1;
    const int zstep = D * Dx;

    int nn[NPT];
    float dx[NPT], dy[NPT], dz[NPT];
    int base[NPT];
    u32x2 P0[NPT], P1[NPT], P2[NPT], P3[NPT];

    #pragma unroll
    for (int i = 0; i < NPT; ++i) {
        int n = t + i * TOT;
        if (n > N - 1) n = N - 1;          // duplicate write of same value: benign
        nn[i] = n;
        float px = __builtin_nontemporal_load(&x[(size_t)n * 3 + 0]);
        float py = __builtin_nontemporal_load(&x[(size_t)n * 3 + 1]);
        float pz = __builtin_nontemporal_load(&x[(size_t)n * 3 + 2]);
        float ux = px * scale, uy = py * scale, uz = pz * scale;
        int ix = (int)ux, iy = (int)uy, iz = (int)uz;   // trunc == floor (x>=0)
        dx[i] = ux - (float)ix;
        dy[i] = uy - (float)iy;
        dz[i] = uz - (float)iz;
        base[i] = (iz * D + iy) * Dx + ix;
    }

    #pragma unroll
    for (int i = 0; i < NPT; ++i) {
        int b = base[i];
        P0[i] = Gp[b];                 // (iy  , iz  ) -> corners v0,v1
        P1[i] = Gp[b + Dx];            // (iy+1, iz  ) -> corners v2,v3
        P2[i] = Gp[b + zstep];         // (iy  , iz+1) -> corners v4,v5
        P3[i] = Gp[b + zstep + Dx];    // (iy+1, iz+1) -> corners v6,v7
    }

    #pragma unroll
    for (int i = 0; i < NPT; ++i) {
        float ax = 0.f, ay = 0.f;
        float wxl = 1.f - dx[i], wxh = dx[i];
        float wyl = 1.f - dy[i], wyh = dy[i];
        float wzl = 1.f - dz[i], wzh = dz[i];
        // corner order v=0..7 preserved: (P0.x,P0.y,P1.x,P1.y,P2.x,P2.y,P3.x,P3.y)
        {
            float2 f0 = unpack16(P0[i].x), f1 = unpack16(P0[i].y);
            float w0 = (wxl * wyl) * wzl, w1 = (wxh * wyl) * wzl;
            ax = fmaf(f0.x, w0, ax); ay = fmaf(f0.y, w0, ay);
            ax = fmaf(f1.x, w1, ax); ay = fmaf(f1.y, w1, ay);
        }
        {
            float2 f0 = unpack16(P1[i].x), f1 = unpack16(P1[i].y);
            float w0 = (wxl * wyh) * wzl, w1 = (wxh * wyh) * wzl;
            ax = fmaf(f0.x, w0, ax); ay = fmaf(f0.y, w0, ay);
            ax = fmaf(f1.x, w1, ax); ay = fmaf(f1.y, w1, ay);
        }
        {
            float2 f0 = unpack16(P2[i].x), f1 = unpack16(P2[i].y);
            float w0 = (wxl * wyl) * wzh, w1 = (wxh * wyl) * wzh;
            ax = fmaf(f0.x, w0, ax); ay = fmaf(f0.y, w0, ay);
            ax = fmaf(f1.x, w1, ax); ay = fmaf(f1.y, w1, ay);
        }
        {
            float2 f0 = unpack16(P3[i].x), f1 = unpack16(P3[i].y);
            float w0 = (wxl * wyh) * wzh, w1 = (wxh * wyh) * wzh;
            ax = fmaf(f0.x, w0, ax); ay = fmaf(f0.y, w0, ay);
            ax = fmaf(f1.x, w1, ax); ay = fmaf(f1.y, w1, ay);
        }
        __builtin_nontemporal_store(packf2(ax, ay), sc + nn[i]);
    }
}

// Hash-table level kernel (round-5 known-good): fp16 table L2-resident,
// even-ix u32x2 pairing -> avg 6 8B-requests/pt.
__global__ __launch_bounds__(256)
void level_kernel(const float* __restrict__ x, const u32* __restrict__ Wl,
                  u32* __restrict__ sc, float scale, int N, int TOT)
{
    int t = blockIdx.x * blockDim.x + threadIdx.x;
    if (t >= TOT) return;

    int nn[NPT];
    float dx[NPT], dy[NPT], dz[NPT];
    u32 a0[NPT], a1[NPT], a2[NPT];
    u32 fv[NPT][8];

    #pragma unroll
    for (int i = 0; i < NPT; ++i) {
        int n = t + i * TOT;
        if (n > N - 1) n = N - 1;
        nn[i] = n;
        float px = __builtin_nontemporal_load(&x[(size_t)n * 3 + 0]);
        float py = __builtin_nontemporal_load(&x[(size_t)n * 3 + 1]);
        float pz = __builtin_nontemporal_load(&x[(size_t)n * 3 + 2]);
        float ux = px * scale, uy = py * scale, uz = pz * scale;
        int ix = (int)ux, iy = (int)uy, iz = (int)uz;
        dx[i] = ux - (float)ix;
        dy[i] = uy - (float)iy;
        dz[i] = uz - (float)iz;
        a0[i] = (unsigned)ix;
        a1[i] = (unsigned)iy * PR1;
        a2[i] = (unsigned)iz * PR2;
    }

    #pragma unroll
    for (int i = 0; i < NPT; ++i) {
        u32 b0 = a0[i] + 1u, b1 = a1[i] + PR1, b2 = a2[i] + PR2;
        u32 E[4] = { a1[i] ^ a2[i], b1 ^ a2[i], a1[i] ^ b2, b1 ^ b2 };
        if ((a0[i] & 1u) == 0u) {
            #pragma unroll
            for (int j = 0; j < 4; ++j) {
                u32 hl = (E[j] ^ a0[i]) & TMASK;       // h_hi = hl ^ 1
                u32x2 p = *reinterpret_cast<const u32x2*>(Wl + (hl & ~1u));
                u32 lo = (hl & 1u) ? p.y : p.x;
                u32 hi = (hl & 1u) ? p.x : p.y;
                fv[i][2 * j + 0] = lo;
                fv[i][2 * j + 1] = hi;
            }
        } else {
            #pragma unroll
            for (int j = 0; j < 4; ++j) {
                u32 hl = (E[j] ^ a0[i]) & TMASK;
                u32 hh = (E[j] ^ b0) & TMASK;
                fv[i][2 * j + 0] = Wl[hl];
                fv[i][2 * j + 1] = Wl[hh];
            }
        }
    }

    #pragma unroll
    for (int i = 0; i < NPT; ++i) {
        float ax = 0.f, ay = 0.f;
        #pragma unroll
        for (int v = 0; v < 8; ++v) {
            float wx = (v & 1) ? dx[i] : 1.f - dx[i];
            float wy = (v & 2) ? dy[i] : 1.f - dy[i];
            float wz = (v & 4) ? dz[i] : 1.f - dz[i];
            float w = (wx * wy) * wz;
            float2 f = unpack16(fv[i][v]);
            ax = fmaf(f.x, w, ax);
            ay = fmaf(f.y, w, ay);
        }
        __builtin_nontemporal_store(packf2(ax, ay), sc + nn[i]);
    }
}

// Assemble 128B output rows from fp16 scratch [l][n] -> out [n][32] f32.
__global__ __launch_bounds__(256)
void transpose_kernel(const u32* __restrict__ sc, float* __restrict__ out, int N)
{
    int n = blockIdx.x * blockDim.x + threadIdx.x;
    if (n >= N) return;
    float r[2 * NLEV];
    #pragma unroll
    for (int l = 0; l < NLEV; ++l) {
        u32 u = __builtin_nontemporal_load(sc + (size_t)l * N + n);
        float2 f = unpack16(u);
        r[2 * l + 0] = f.x;
        r[2 * l + 1] = f.y;
    }
    f32x4* o = reinterpret_cast<f32x4*>(out + (size_t)n * (2 * NLEV));
    #pragma unroll
    for (int j = 0; j < 8; ++j) {
        f32x4 v = { r[4 * j + 0], r[4 * j + 1], r[4 * j + 2], r[4 * j + 3] };
        o[j] = v;   // regular store: L2 merges 16B pieces into full lines
    }
}

// ---------------- fallback (round-1 kernel, known-good, f32 exact) ----------
__global__ __launch_bounds__(256)
void hashenc_fallback(const float* __restrict__ x, const float* __restrict__ W,
                      float* __restrict__ out, ScaleArgs sc, int N)
{
    int n = blockIdx.x * blockDim.x + threadIdx.x;
    if (n >= N) return;
    float px = x[(size_t)n * 3 + 0];
    float py = x[(size_t)n * 3 + 1];
    float pz = x[(size_t)n * 3 + 2];
    float acc[2 * NLEV];
    #pragma unroll
    for (int l = 0; l < NLEV; ++l) {
        float s = sc.s[l];
        float ux = px * s, uy = py * s, uz = pz * s;
        int ix = (int)ux, iy = (int)uy, iz = (int)uz;
        float dx = ux - (float)ix, dy = uy - (float)iy, dz = uz - (float)iz;
        unsigned a0 = (unsigned)ix;
        unsigned a1 = (unsigned)iy * PR1;
        unsigned a2 = (unsigned)iz * PR2;
        unsigned b0 = a0 + 1u, b1 = a1 + PR1, b2 = a2 + PR2;
        const float* Wl = W + (size_t)l * TBLN * 2u;
        float ax = 0.f, ay = 0.f;
        #pragma unroll
        for (int v = 0; v < 8; ++v) {
            unsigned h = ((v & 1) ? b0 : a0) ^ ((v & 2) ? b1 : a1) ^ ((v & 4) ? b2 : a2);
            h &= TMASK;
            float wx = (v & 1) ? dx : 1.f - dx;
            float wy = (v & 2) ? dy : 1.f - dy;
            float wz = (v & 4) ? dz : 1.f - dz;
            float w = (wx * wy) * wz;
            const float2 fvv = *reinterpret_cast<const float2*>(Wl + (size_t)h * 2u);
            ax = fmaf(fvv.x, w, ax);
            ay = fmaf(fvv.y, w, ay);
        }
        acc[2 * l + 0] = ax;
        acc[2 * l + 1] = ay;
    }
    float4* o = reinterpret_cast<float4*>(out + (size_t)n * (2 * NLEV));
    #pragma unroll
    for (int j = 0; j < 8; ++j)
        o[j] = make_float4(acc[4 * j + 0], acc[4 * j + 1], acc[4 * j + 2], acc[4 * j + 3]);
}

extern "C" void kernel_launch(void* const* d_in, const int* in_sizes, int n_in,
                              void* d_out, int out_size, void* d_ws, size_t ws_size,
                              hipStream_t stream) {
    const float* x = (const float*)d_in[0];
    const float* W = (const float*)d_in[1];
    float* out = (float*)d_out;
    int N = in_sizes[0] / 3;

    // numpy-exact scales: b = exp((log(2048)-log(16))/16); s_l = float32(16*b**l)
    ScaleArgs sc;
    double b = exp((log(2048.0) - log(16.0)) / 16.0);
    for (int l = 0; l < NLEV; ++l) {
        double p;
        switch (l) {
            case 0: p = 1.0; break;
            case 1: p = b;   break;
            case 2: p = b * b; break;
            default: p = pow(b, (double)l); break;
        }
        sc.s[l] = (float)(16.0 * p);
    }

    // dense grid geometry for levels 0..NDENSE-1
    int Dl[NDENSE];
    size_t pcnt[NDENSE], poff[NDENSE], dtot = 0;
    for (int l = 0; l < NDENSE; ++l) {
        int D = (int)floor((double)sc.s[l]) + 2;      // vertices 0..D-1 cover ix+1
        Dl[l] = D;
        pcnt[l] = (size_t)(D - 1) * (size_t)D * (size_t)D;
        poff[l] = dtot;
        dtot += pcnt[l];
    }

    size_t whalf_u32 = (size_t)NLEV * TBLN;           // 33.5MB fp16 tables
    size_t scratch_u32 = (size_t)NLEV * (size_t)N;    // 128MB fp16 scratch
    size_t need_hash = (whalf_u32 + scratch_u32) * sizeof(u32);
    size_t need_full = need_hash + dtot * sizeof(u32x2);

    if (ws_size >= need_hash) {
        bool use_dense = (ws_size >= need_full);
        u32* Wh = (u32*)d_ws;
        u32* scratch = Wh + whalf_u32;
        u32x2* Gp = reinterpret_cast<u32x2*>(scratch + scratch_u32);

        int np4 = (int)(whalf_u32 / 4);
        hipLaunchKernelGGL(convert_w, dim3((np4 + 255) / 256), dim3(256), 0, stream,
                           W, Wh, np4);

        if (use_dense) {
            for (int l = 0; l < NDENSE; ++l) {
                int P = (int)pcnt[l];
                hipLaunchKernelGGL(build_dense, dim3((P + 255) / 256), dim3(256), 0, stream,
                                   Wh + (size_t)l * TBLN, Gp + poff[l], Dl[l], P);
            }
        }

        int TOT = (N + NPT - 1) / NPT;
        int gl = (TOT + 255) / 256;
        for (int l = 0; l < NLEV; ++l) {
            if (use_dense && l < NDENSE) {
                hipLaunchKernelGGL(level_dense, dim3(gl), dim3(256), 0, stream,
                                   x, Gp + poff[l],
                                   scratch + (size_t)l * (size_t)N,
                                   sc.s[l], Dl[l], N, TOT);
            } else {
                hipLaunchKernelGGL(level_kernel, dim3(gl), dim3(256), 0, stream,
                                   x, Wh + (size_t)l * TBLN,
                                   scratch + (size_t)l * (size_t)N,
                                   sc.s[l], N, TOT);
            }
        }
        int gt = (N + 255) / 256;
        hipLaunchKernelGGL(transpose_kernel, dim3(gt), dim3(256), 0, stream,
                           scratch, out, N);
    } else {
        int grid = (N + 255) / 256;
        hipLaunchKernelGGL(hashenc_fallback, dim3(grid), dim3(256), 0, stream,
                           x, W, out, sc, N);
    }
}

// Round 8
// 687.308 us; speedup vs baseline: 1.1019x; 1.0711x over previous
//
#include <hip/hip_runtime.h>
#include <hip/hip_fp16.h>
#include <math.h>

#define NLEV 16
#define NDENSE 5          // levels 0..4 -> dense pair-duplicated grids (<=1.4MB each)
#define TBLN (1u << 19)
#define TMASK (TBLN - 1u)
#define NPT 4             // points per thread in level kernels
#define PR1 2654435761u
#define PR2 805459861u

typedef float f32x4 __attribute__((ext_vector_type(4)));
typedef unsigned int u32;
typedef unsigned int u32x2 __attribute__((ext_vector_type(2)));
typedef unsigned int u32x4 __attribute__((ext_vector_type(4)));

struct ScaleArgs { float s[NLEV]; };

// dense geometry, compile-time (scales are fixed: 16, 21.68, 29.37, 39.79, 53.90)
// D = floor(s)+2 ; pair-grid entries = (D-1)*D*D ; offsets = prefix sum
#define DD0 18
#define DD1 23
#define DD2 31
#define DD3 41
#define DD4 55
#define DO0 0
#define DO1 5508      /* 17*18*18 */
#define DO2 17146     /* +22*23*23 */
#define DO3 45976     /* +30*31*31 */
#define DO4 113216    /* +40*41*41 */
#define DTOT 276566   /* +54*55*55 */

static __device__ __forceinline__ u32 packf2(float a, float b) {
    __half2 h = __floats2half2_rn(a, b);          // low16 = a, high16 = b
    return __builtin_bit_cast(u32, h);
}
static __device__ __forceinline__ float2 unpack16(u32 u) {
    __half2 h = __builtin_bit_cast(__half2, u);
    return __half22float2(h);                      // .x = low half
}

// W f32 (levels 5..15) -> packed fp16 pairs, one u32 per table entry
__global__ __launch_bounds__(256)
void convert_w(const float* __restrict__ W, u32* __restrict__ Wh, int np4)
{
    int i = blockIdx.x * blockDim.x + threadIdx.x;
    if (i >= np4) return;
    const f32x4* src = reinterpret_cast<const f32x4*>(W) + (size_t)i * 2;
    f32x4 A = __builtin_nontemporal_load(src);
    f32x4 B = __builtin_nontemporal_load(src + 1);
    u32x4 o = { packf2(A.x, A.y), packf2(A.z, A.w),
                packf2(B.x, B.y), packf2(B.z, B.w) };
    __builtin_nontemporal_store(o, reinterpret_cast<u32x4*>(Wh) + i);
}

// Dense pair-duplicated grid built DIRECTLY from f32 W (bit-identical packing
// to convert_w): Gp[(iz*D+iy)*(D-1)+ix] = (pack(W[h(ix)]), pack(W[h(ix+1)]))
__global__ __launch_bounds__(256)
void build_dense(const float* __restrict__ Wlf, u32x2* __restrict__ Gpl, int D, int P)
{
    int v = blockIdx.x * blockDim.x + threadIdx.x;
    if (v >= P) return;
    int Dx = D - 1;
    int ix = v % Dx;
    int rest = v / Dx;
    int iy = rest % D;
    int iz = rest / D;
    u32 e = ((u32)iy * PR1) ^ ((u32)iz * PR2);
    u32 h0 = (e ^ (u32)ix) & TMASK;
    u32 h1 = (e ^ (u32)(ix + 1)) & TMASK;
    float2 f0 = *reinterpret_cast<const float2*>(Wlf + (size_t)h0 * 2u);
    float2 f1 = *reinterpret_cast<const float2*>(Wlf + (size_t)h1 * 2u);
    u32x2 o = { packf2(f0.x, f0.y), packf2(f1.x, f1.y) };
    Gpl[v] = o;
}

// ---- per-level bodies (called from the fused kernel; lvl is block-uniform) ----

// dense: exactly 4 aligned 8B gathers per point (one per (y,z) corner pair)
template<int D>
static __device__ __forceinline__ void dense_body(
    const float* __restrict__ x, const u32x2* __restrict__ Gp,
    u32* __restrict__ scl, float scale, int N, int TOT, int t)
{
    constexpr int Dx = D - 1;
    constexpr int zstep = D * Dx;

    int nn[NPT];
    float dx[NPT], dy[NPT], dz[NPT];
    int base[NPT];
    u32x2 P0[NPT], P1[NPT], P2[NPT], P3[NPT];

    #pragma unroll
    for (int i = 0; i < NPT; ++i) {
        int n = t + i * TOT;
        if (n > N - 1) n = N - 1;          // duplicate write of same value: benign
        nn[i] = n;
        float px = __builtin_nontemporal_load(&x[(size_t)n * 3 + 0]);
        float py = __builtin_nontemporal_load(&x[(size_t)n * 3 + 1]);
        float pz = __builtin_nontemporal_load(&x[(size_t)n * 3 + 2]);
        float ux = px * scale, uy = py * scale, uz = pz * scale;
        int ix = (int)ux, iy = (int)uy, iz = (int)uz;   // trunc == floor (x>=0)
        dx[i] = ux - (float)ix;
        dy[i] = uy - (float)iy;
        dz[i] = uz - (float)iz;
        base[i] = (iz * D + iy) * Dx + ix;
    }

    #pragma unroll
    for (int i = 0; i < NPT; ++i) {
        int b = base[i];
        P0[i] = Gp[b];                 // corners v0,v1 (iy, iz)
        P1[i] = Gp[b + Dx];            // v2,v3 (iy+1, iz)
        P2[i] = Gp[b + zstep];         // v4,v5 (iy, iz+1)
        P3[i] = Gp[b + zstep + Dx];    // v6,v7 (iy+1, iz+1)
    }

    #pragma unroll
    for (int i = 0; i < NPT; ++i) {
        float ax = 0.f, ay = 0.f;
        float wxl = 1.f - dx[i], wxh = dx[i];
        float wyl = 1.f - dy[i], wyh = dy[i];
        float wzl = 1.f - dz[i], wzh = dz[i];
        {
            float2 f0 = unpack16(P0[i].x), f1 = unpack16(P0[i].y);
            float w0 = (wxl * wyl) * wzl, w1 = (wxh * wyl) * wzl;
            ax = fmaf(f0.x, w0, ax); ay = fmaf(f0.y, w0, ay);
            ax = fmaf(f1.x, w1, ax); ay = fmaf(f1.y, w1, ay);
        }
        {
            float2 f0 = unpack16(P1[i].x), f1 = unpack16(P1[i].y);
            float w0 = (wxl * wyh) * wzl, w1 = (wxh * wyh) * wzl;
            ax = fmaf(f0.x, w0, ax); ay = fmaf(f0.y, w0, ay);
            ax = fmaf(f1.x, w1, ax); ay = fmaf(f1.y, w1, ay);
        }
        {
            float2 f0 = unpack16(P2[i].x), f1 = unpack16(P2[i].y);
            float w0 = (wxl * wyl) * wzh, w1 = (wxh * wyl) * wzh;
            ax = fmaf(f0.x, w0, ax); ay = fmaf(f0.y, w0, ay);
            ax = fmaf(f1.x, w1, ax); ay = fmaf(f1.y, w1, ay);
        }
        {
            float2 f0 = unpack16(P3[i].x), f1 = unpack16(P3[i].y);
            float w0 = (wxl * wyh) * wzh, w1 = (wxh * wyh) * wzh;
            ax = fmaf(f0.x, w0, ax); ay = fmaf(f0.y, w0, ay);
            ax = fmaf(f1.x, w1, ax); ay = fmaf(f1.y, w1, ay);
        }
        __builtin_nontemporal_store(packf2(ax, ay), scl + nn[i]);
    }
}

// hash: round-5 known-good even-ix pairing, avg 6 8B-requests/pt
static __device__ __forceinline__ void hash_body(
    const float* __restrict__ x, const u32* __restrict__ Wl,
    u32* __restrict__ scl, float scale, int N, int TOT, int t)
{
    int nn[NPT];
    float dx[NPT], dy[NPT], dz[NPT];
    u32 a0[NPT], a1[NPT], a2[NPT];
    u32 fv[NPT][8];

    #pragma unroll
    for (int i = 0; i < NPT; ++i) {
        int n = t + i * TOT;
        if (n > N - 1) n = N - 1;
        nn[i] = n;
        float px = __builtin_nontemporal_load(&x[(size_t)n * 3 + 0]);
        float py = __builtin_nontemporal_load(&x[(size_t)n * 3 + 1]);
        float pz = __builtin_nontemporal_load(&x[(size_t)n * 3 + 2]);
        float ux = px * scale, uy = py * scale, uz = pz * scale;
        int ix = (int)ux, iy = (int)uy, iz = (int)uz;
        dx[i] = ux - (float)ix;
        dy[i] = uy - (float)iy;
        dz[i] = uz - (float)iz;
        a0[i] = (unsigned)ix;
        a1[i] = (unsigned)iy * PR1;
        a2[i] = (unsigned)iz * PR2;
    }

    #pragma unroll
    for (int i = 0; i < NPT; ++i) {
        u32 b0 = a0[i] + 1u, b1 = a1[i] + PR1, b2 = a2[i] + PR2;
        u32 E[4] = { a1[i] ^ a2[i], b1 ^ a2[i], a1[i] ^ b2, b1 ^ b2 };
        if ((a0[i] & 1u) == 0u) {
            #pragma unroll
            for (int j = 0; j < 4; ++j) {
                u32 hl = (E[j] ^ a0[i]) & TMASK;       // h_hi = hl ^ 1
                u32x2 p = *reinterpret_cast<const u32x2*>(Wl + (hl & ~1u));
                u32 lo = (hl & 1u) ? p.y : p.x;
                u32 hi = (hl & 1u) ? p.x : p.y;
                fv[i][2 * j + 0] = lo;
                fv[i][2 * j + 1] = hi;
            }
        } else {
            #pragma unroll
            for (int j = 0; j < 4; ++j) {
                u32 hl = (E[j] ^ a0[i]) & TMASK;
                u32 hh = (E[j] ^ b0) & TMASK;
                fv[i][2 * j + 0] = Wl[hl];
                fv[i][2 * j + 1] = Wl[hh];
            }
        }
    }

    #pragma unroll
    for (int i = 0; i < NPT; ++i) {
        float ax = 0.f, ay = 0.f;
        #pragma unroll
        for (int v = 0; v < 8; ++v) {
            float wx = (v & 1) ? dx[i] : 1.f - dx[i];
            float wy = (v & 2) ? dy[i] : 1.f - dy[i];
            float wz = (v & 4) ? dz[i] : 1.f - dz[i];
            float w = (wx * wy) * wz;
            float2 f = unpack16(fv[i][v]);
            ax = fmaf(f.x, w, ax);
            ay = fmaf(f.y, w, ay);
        }
        __builtin_nontemporal_store(packf2(ax, ay), scl + nn[i]);
    }
}

// One fused kernel for all 16 levels. Blocks are level-major: sequential
// dispatch keeps device-wide one-table-at-a-time L2 locality AND removes the
// 15 inter-kernel ramp/drain boundaries.
__global__ __launch_bounds__(256)
void fused_levels(const float* __restrict__ x, const u32* __restrict__ Wh,
                  const u32x2* __restrict__ Gp, u32* __restrict__ scratch,
                  ScaleArgs sc, int N, int TOT, int BPL)
{
    int lvl = blockIdx.x / BPL;
    int t = (blockIdx.x - lvl * BPL) * blockDim.x + threadIdx.x;
    if (t >= TOT) return;
    float scale = sc.s[lvl];
    u32* scl = scratch + (size_t)lvl * (size_t)N;

    switch (lvl) {   // block-uniform
        case 0: dense_body<DD0>(x, Gp + DO0, scl, scale, N, TOT, t); break;
        case 1: dense_body<DD1>(x, Gp + DO1, scl, scale, N, TOT, t); break;
        case 2: dense_body<DD2>(x, Gp + DO2, scl, scale, N, TOT, t); break;
        case 3: dense_body<DD3>(x, Gp + DO3, scl, scale, N, TOT, t); break;
        case 4: dense_body<DD4>(x, Gp + DO4, scl, scale, N, TOT, t); break;
        default:
            hash_body(x, Wh + (size_t)(lvl - NDENSE) * TBLN, scl, scale, N, TOT, t);
            break;
    }
}

// Assemble 128B output rows from fp16 scratch [l][n] -> out [n][32] f32.
__global__ __launch_bounds__(256)
void transpose_kernel(const u32* __restrict__ sc, float* __restrict__ out, int N)
{
    int n = blockIdx.x * blockDim.x + threadIdx.x;
    if (n >= N) return;
    float r[2 * NLEV];
    #pragma unroll
    for (int l = 0; l < NLEV; ++l) {
        u32 u = __builtin_nontemporal_load(sc + (size_t)l * N + n);
        float2 f = unpack16(u);
        r[2 * l + 0] = f.x;
        r[2 * l + 1] = f.y;
    }
    f32x4* o = reinterpret_cast<f32x4*>(out + (size_t)n * (2 * NLEV));
    #pragma unroll
    for (int j = 0; j < 8; ++j) {
        f32x4 v = { r[4 * j + 0], r[4 * j + 1], r[4 * j + 2], r[4 * j + 3] };
        o[j] = v;   // regular store: L2 merges 16B pieces into full lines
    }
}

// ---------------- fallback (round-1 kernel, known-good, f32 exact) ----------
__global__ __launch_bounds__(256)
void hashenc_fallback(const float* __restrict__ x, const float* __restrict__ W,
                      float* __restrict__ out, ScaleArgs sc, int N)
{
    int n = blockIdx.x * blockDim.x + threadIdx.x;
    if (n >= N) return;
    float px = x[(size_t)n * 3 + 0];
    float py = x[(size_t)n * 3 + 1];
    float pz = x[(size_t)n * 3 + 2];
    float acc[2 * NLEV];
    #pragma unroll
    for (int l = 0; l < NLEV; ++l) {
        float s = sc.s[l];
        float ux = px * s, uy = py * s, uz = pz * s;
        int ix = (int)ux, iy = (int)uy, iz = (int)uz;
        float dx = ux - (float)ix, dy = uy - (float)iy, dz = uz - (float)iz;
        unsigned a0 = (unsigned)ix;
        unsigned a1 = (unsigned)iy * PR1;
        unsigned a2 = (unsigned)iz * PR2;
        unsigned b0 = a0 + 1u, b1 = a1 + PR1, b2 = a2 + PR2;
        const float* Wl = W + (size_t)l * TBLN * 2u;
        float ax = 0.f, ay = 0.f;
        #pragma unroll
        for (int v = 0; v < 8; ++v) {
            unsigned h = ((v & 1) ? b0 : a0) ^ ((v & 2) ? b1 : a1) ^ ((v & 4) ? b2 : a2);
            h &= TMASK;
            float wx = (v & 1) ? dx : 1.f - dx;
            float wy = (v & 2) ? dy : 1.f - dy;
            float wz = (v & 4) ? dz : 1.f - dz;
            float w = (wx * wy) * wz;
            const float2 fvv = *reinterpret_cast<const float2*>(Wl + (size_t)h * 2u);
            ax = fmaf(fvv.x, w, ax);
            ay = fmaf(fvv.y, w, ay);
        }
        acc[2 * l + 0] = ax;
        acc[2 * l + 1] = ay;
    }
    float4* o = reinterpret_cast<float4*>(out + (size_t)n * (2 * NLEV));
    #pragma unroll
    for (int j = 0; j < 8; ++j)
        o[j] = make_float4(acc[4 * j + 0], acc[4 * j + 1], acc[4 * j + 2], acc[4 * j + 3]);
}

extern "C" void kernel_launch(void* const* d_in, const int* in_sizes, int n_in,
                              void* d_out, int out_size, void* d_ws, size_t ws_size,
                              hipStream_t stream) {
    const float* x = (const float*)d_in[0];
    const float* W = (const float*)d_in[1];
    float* out = (float*)d_out;
    int N = in_sizes[0] / 3;

    // numpy-exact scales: b = exp((log(2048)-log(16))/16); s_l = float32(16*b**l)
    ScaleArgs sc;
    double b = exp((log(2048.0) - log(16.0)) / 16.0);
    for (int l = 0; l < NLEV; ++l) {
        double p;
        switch (l) {
            case 0: p = 1.0; break;
            case 1: p = b;   break;
            case 2: p = b * b; break;
            default: p = pow(b, (double)l); break;
        }
        sc.s[l] = (float)(16.0 * p);
    }

    // workspace layout (u32 units): [Wh: 11 fine tables][Gp: dense pair-grids][scratch]
    size_t wh_u32 = (size_t)(NLEV - NDENSE) * TBLN;   // 23.1 MB
    size_t gp_u32 = (size_t)DTOT * 2u;                // 2.2 MB
    size_t scr_u32 = (size_t)NLEV * (size_t)N;        // 128 MB
    size_t need = (wh_u32 + gp_u32 + scr_u32) * sizeof(u32);   // ~153.3 MB

    if (ws_size >= need) {
        u32* Wh = (u32*)d_ws;
        u32x2* Gp = reinterpret_cast<u32x2*>(Wh + wh_u32);
        u32* scratch = Wh + wh_u32 + gp_u32;

        // fp16 tables for hash levels 5..15
        int np4 = (int)(wh_u32 / 4);
        hipLaunchKernelGGL(convert_w, dim3((np4 + 255) / 256), dim3(256), 0, stream,
                           W + (size_t)NDENSE * TBLN * 2u, Wh, np4);

        // dense pair-grids for levels 0..4 directly from f32 W (bit-identical pack)
        const int Dl[NDENSE] = { DD0, DD1, DD2, DD3, DD4 };
        const int Ol[NDENSE] = { DO0, DO1, DO2, DO3, DO4 };
        for (int l = 0; l < NDENSE; ++l) {
            int P = (Dl[l] - 1) * Dl[l] * Dl[l];
            hipLaunchKernelGGL(build_dense, dim3((P + 255) / 256), dim3(256), 0, stream,
                               W + (size_t)l * TBLN * 2u, Gp + Ol[l], Dl[l], P);
        }

        int TOT = (N + NPT - 1) / NPT;
        int BPL = (TOT + 255) / 256;
        hipLaunchKernelGGL(fused_levels, dim3(NLEV * BPL), dim3(256), 0, stream,
                           x, Wh, Gp, scratch, sc, N, TOT, BPL);

        int gt = (N + 255) / 256;
        hipLaunchKernelGGL(transpose_kernel, dim3(gt), dim3(256), 0, stream,
                           scratch, out, N);
    } else {
        int grid = (N + 255) / 256;
        hipLaunchKernelGGL(hashenc_fallback, dim3(grid), dim3(256), 0, stream,
                           x, W, out, sc, N);
    }
}

// Round 9
// 636.118 us; speedup vs baseline: 1.1905x; 1.0805x over previous
//
#include <hip/hip_runtime.h>
#include <hip/hip_fp16.h>
#include <math.h>

#define NLEV 16
#define TBLN (1u << 19)
#define TMASK (TBLN - 1u)
#define NPT 4             // points per thread in fused level kernel
#define NPTL 16           // points per thread in LDS level kernels
#define PR1 2654435761u
#define PR2 805459861u

typedef float f32x4 __attribute__((ext_vector_type(4)));
typedef unsigned int u32;
typedef unsigned int u32x2 __attribute__((ext_vector_type(2)));
typedef unsigned int u32x4 __attribute__((ext_vector_type(4)));

struct ScaleArgs { float s[NLEV]; };

// ---- compile-time geometry (scales fixed: 16,21.7,29.4,39.8,53.9,73.0,...) ----
// LDS levels 0,1: unpaired u32 grids D^3
#define DU0 18
#define DU1 23
#define GU0 0
#define GU1 5832            /* 18^3 */
#define GUTOT 17999         /* + 23^3 */
// L2 dense levels 2..5: x-pair-duplicated grids (D-1)*D*D of u32x2
#define DD2 31
#define DD3 41
#define DD4 55
#define DD5 75
#define GO2 0
#define GO3 28830           /* 30*31*31 */
#define GO4 96070           /* +40*41*41 */
#define GO5 259420          /* +54*55*55 */
#define GPTOT 675670        /* +74*75*75 */

static __device__ __forceinline__ u32 packf2(float a, float b) {
    __half2 h = __floats2half2_rn(a, b);          // low16 = a, high16 = b
    return __builtin_bit_cast(u32, h);
}
static __device__ __forceinline__ float2 unpack16(u32 u) {
    __half2 h = __builtin_bit_cast(__half2, u);
    return __half22float2(h);                      // .x = low half
}

// W f32 (levels 6..15) -> packed fp16 pairs, one u32 per table entry
__global__ __launch_bounds__(256)
void convert_w(const float* __restrict__ W, u32* __restrict__ Wh, int np4)
{
    int i = blockIdx.x * blockDim.x + threadIdx.x;
    if (i >= np4) return;
    const f32x4* src = reinterpret_cast<const f32x4*>(W) + (size_t)i * 2;
    f32x4 A = __builtin_nontemporal_load(src);
    f32x4 B = __builtin_nontemporal_load(src + 1);
    u32x4 o = { packf2(A.x, A.y), packf2(A.z, A.w),
                packf2(B.x, B.y), packf2(B.z, B.w) };
    __builtin_nontemporal_store(o, reinterpret_cast<u32x4*>(Wh) + i);
}

// unpaired dense grid G[iz][iy][ix] (stride D), from f32 W, bit-identical pack
__global__ __launch_bounds__(256)
void build_unpaired(const float* __restrict__ Wlf, u32* __restrict__ Gu, int D, int P)
{
    int v = blockIdx.x * blockDim.x + threadIdx.x;
    if (v >= P) return;
    int ix = v % D;
    int rest = v / D;
    int iy = rest % D;
    int iz = rest / D;
    u32 h = (((u32)iy * PR1) ^ ((u32)iz * PR2) ^ (u32)ix) & TMASK;
    float2 f = *reinterpret_cast<const float2*>(Wlf + (size_t)h * 2u);
    Gu[v] = packf2(f.x, f.y);
}

// x-pair-duplicated grid Gp[(iz*D+iy)*(D-1)+ix] = (pack(W[h(ix)]), pack(W[h(ix+1)]))
__global__ __launch_bounds__(256)
void build_dense(const float* __restrict__ Wlf, u32x2* __restrict__ Gpl, int D, int P)
{
    int v = blockIdx.x * blockDim.x + threadIdx.x;
    if (v >= P) return;
    int Dx = D - 1;
    int ix = v % Dx;
    int rest = v / Dx;
    int iy = rest % D;
    int iz = rest / D;
    u32 e = ((u32)iy * PR1) ^ ((u32)iz * PR2);
    u32 h0 = (e ^ (u32)ix) & TMASK;
    u32 h1 = (e ^ (u32)(ix + 1)) & TMASK;
    float2 f0 = *reinterpret_cast<const float2*>(Wlf + (size_t)h0 * 2u);
    float2 f1 = *reinterpret_cast<const float2*>(Wlf + (size_t)h1 * 2u);
    u32x2 o = { packf2(f0.x, f0.y), packf2(f1.x, f1.y) };
    Gpl[v] = o;
}

// ---- LDS level kernel (levels 0,1): grid fits in static LDS; gathers cost
// ZERO L2 slots. Staging is coalesced and amortized over 4096 pts/block. ----
template<int D>
__global__ __launch_bounds__(256)
void lds_level(const float* __restrict__ x, const u32* __restrict__ Gu,
               u32* __restrict__ scl, float scale, int N)
{
    __shared__ u32 g[D * D * D];
    for (int i = threadIdx.x; i < D * D * D; i += 256) g[i] = Gu[i];
    __syncthreads();

    int base = blockIdx.x * (256 * NPTL);
    #pragma unroll 4
    for (int i = 0; i < NPTL; ++i) {
        int n = base + i * 256 + (int)threadIdx.x;
        if (n < N) {
            float px = __builtin_nontemporal_load(&x[(size_t)n * 3 + 0]);
            float py = __builtin_nontemporal_load(&x[(size_t)n * 3 + 1]);
            float pz = __builtin_nontemporal_load(&x[(size_t)n * 3 + 2]);
            float ux = px * scale, uy = py * scale, uz = pz * scale;
            int ix = (int)ux, iy = (int)uy, iz = (int)uz;
            float dx = ux - (float)ix, dy = uy - (float)iy, dz = uz - (float)iz;
            int b = (iz * D + iy) * D + ix;
            u32 c0 = g[b],             c1 = g[b + 1];
            u32 c2 = g[b + D],         c3 = g[b + D + 1];
            u32 c4 = g[b + D * D],     c5 = g[b + D * D + 1];
            u32 c6 = g[b + D * D + D], c7 = g[b + D * D + D + 1];
            float wxl = 1.f - dx, wxh = dx;
            float wyl = 1.f - dy, wyh = dy;
            float wzl = 1.f - dz, wzh = dz;
            float ax = 0.f, ay = 0.f;
            float2 f;
            f = unpack16(c0); { float w = (wxl * wyl) * wzl; ax = fmaf(f.x, w, ax); ay = fmaf(f.y, w, ay); }
            f = unpack16(c1); { float w = (wxh * wyl) * wzl; ax = fmaf(f.x, w, ax); ay = fmaf(f.y, w, ay); }
            f = unpack16(c2); { float w = (wxl * wyh) * wzl; ax = fmaf(f.x, w, ax); ay = fmaf(f.y, w, ay); }
            f = unpack16(c3); { float w = (wxh * wyh) * wzl; ax = fmaf(f.x, w, ax); ay = fmaf(f.y, w, ay); }
            f = unpack16(c4); { float w = (wxl * wyl) * wzh; ax = fmaf(f.x, w, ax); ay = fmaf(f.y, w, ay); }
            f = unpack16(c5); { float w = (wxh * wyl) * wzh; ax = fmaf(f.x, w, ax); ay = fmaf(f.y, w, ay); }
            f = unpack16(c6); { float w = (wxl * wyh) * wzh; ax = fmaf(f.x, w, ax); ay = fmaf(f.y, w, ay); }
            f = unpack16(c7); { float w = (wxh * wyh) * wzh; ax = fmaf(f.x, w, ax); ay = fmaf(f.y, w, ay); }
            __builtin_nontemporal_store(packf2(ax, ay), scl + n);
        }
    }
}

// ---- fused-kernel per-level bodies (lvl is block-uniform) ----

// L2-dense: exactly 4 aligned 8B gathers per point
template<int D>
static __device__ __forceinline__ void dense_body(
    const float* __restrict__ x, const u32x2* __restrict__ Gp,
    u32* __restrict__ scl, float scale, int N, int TOT, int t)
{
    constexpr int Dx = D - 1;
    constexpr int zstep = D * Dx;

    int nn[NPT];
    float dx[NPT], dy[NPT], dz[NPT];
    int base[NPT];
    u32x2 P0[NPT], P1[NPT], P2[NPT], P3[NPT];

    #pragma unroll
    for (int i = 0; i < NPT; ++i) {
        int n = t + i * TOT;
        if (n > N - 1) n = N - 1;          // duplicate write of same value: benign
        nn[i] = n;
        float px = __builtin_nontemporal_load(&x[(size_t)n * 3 + 0]);
        float py = __builtin_nontemporal_load(&x[(size_t)n * 3 + 1]);
        float pz = __builtin_nontemporal_load(&x[(size_t)n * 3 + 2]);
        float ux = px * scale, uy = py * scale, uz = pz * scale;
        int ix = (int)ux, iy = (int)uy, iz = (int)uz;
        dx[i] = ux - (float)ix;
        dy[i] = uy - (float)iy;
        dz[i] = uz - (float)iz;
        base[i] = (iz * D + iy) * Dx + ix;
    }

    #pragma unroll
    for (int i = 0; i < NPT; ++i) {
        int b = base[i];
        P0[i] = Gp[b];
        P1[i] = Gp[b + Dx];
        P2[i] = Gp[b + zstep];
        P3[i] = Gp[b + zstep + Dx];
    }

    #pragma unroll
    for (int i = 0; i < NPT; ++i) {
        float ax = 0.f, ay = 0.f;
        float wxl = 1.f - dx[i], wxh = dx[i];
        float wyl = 1.f - dy[i], wyh = dy[i];
        float wzl = 1.f - dz[i], wzh = dz[i];
        {
            float2 f0 = unpack16(P0[i].x), f1 = unpack16(P0[i].y);
            float w0 = (wxl * wyl) * wzl, w1 = (wxh * wyl) * wzl;
            ax = fmaf(f0.x, w0, ax); ay = fmaf(f0.y, w0, ay);
            ax = fmaf(f1.x, w1, ax); ay = fmaf(f1.y, w1, ay);
        }
        {
            float2 f0 = unpack16(P1[i].x), f1 = unpack16(P1[i].y);
            float w0 = (wxl * wyh) * wzl, w1 = (wxh * wyh) * wzl;
            ax = fmaf(f0.x, w0, ax); ay = fmaf(f0.y, w0, ay);
            ax = fmaf(f1.x, w1, ax); ay = fmaf(f1.y, w1, ay);
        }
        {
            float2 f0 = unpack16(P2[i].x), f1 = unpack16(P2[i].y);
            float w0 = (wxl * wyl) * wzh, w1 = (wxh * wyl) * wzh;
            ax = fmaf(f0.x, w0, ax); ay = fmaf(f0.y, w0, ay);
            ax = fmaf(f1.x, w1, ax); ay = fmaf(f1.y, w1, ay);
        }
        {
            float2 f0 = unpack16(P3[i].x), f1 = unpack16(P3[i].y);
            float w0 = (wxl * wyh) * wzh, w1 = (wxh * wyh) * wzh;
            ax = fmaf(f0.x, w0, ax); ay = fmaf(f0.y, w0, ay);
            ax = fmaf(f1.x, w1, ax); ay = fmaf(f1.y, w1, ay);
        }
        __builtin_nontemporal_store(packf2(ax, ay), scl + nn[i]);
    }
}

// hash: even-ix u32x2 pairing, avg 6 8B-requests/pt
static __device__ __forceinline__ void hash_body(
    const float* __restrict__ x, const u32* __restrict__ Wl,
    u32* __restrict__ scl, float scale, int N, int TOT, int t)
{
    int nn[NPT];
    float dx[NPT], dy[NPT], dz[NPT];
    u32 a0[NPT], a1[NPT], a2[NPT];
    u32 fv[NPT][8];

    #pragma unroll
    for (int i = 0; i < NPT; ++i) {
        int n = t + i * TOT;
        if (n > N - 1) n = N - 1;
        nn[i] = n;
        float px = __builtin_nontemporal_load(&x[(size_t)n * 3 + 0]);
        float py = __builtin_nontemporal_load(&x[(size_t)n * 3 + 1]);
        float pz = __builtin_nontemporal_load(&x[(size_t)n * 3 + 2]);
        float ux = px * scale, uy = py * scale, uz = pz * scale;
        int ix = (int)ux, iy = (int)uy, iz = (int)uz;
        dx[i] = ux - (float)ix;
        dy[i] = uy - (float)iy;
        dz[i] = uz - (float)iz;
        a0[i] = (unsigned)ix;
        a1[i] = (unsigned)iy * PR1;
        a2[i] = (unsigned)iz * PR2;
    }

    #pragma unroll
    for (int i = 0; i < NPT; ++i) {
        u32 b0 = a0[i] + 1u, b1 = a1[i] + PR1, b2 = a2[i] + PR2;
        u32 E[4] = { a1[i] ^ a2[i], b1 ^ a2[i], a1[i] ^ b2, b1 ^ b2 };
        if ((a0[i] & 1u) == 0u) {
            #pragma unroll
            for (int j = 0; j < 4; ++j) {
                u32 hl = (E[j] ^ a0[i]) & TMASK;       // h_hi = hl ^ 1
                u32x2 p = *reinterpret_cast<const u32x2*>(Wl + (hl & ~1u));
                u32 lo = (hl & 1u) ? p.y : p.x;
                u32 hi = (hl & 1u) ? p.x : p.y;
                fv[i][2 * j + 0] = lo;
                fv[i][2 * j + 1] = hi;
            }
        } else {
            #pragma unroll
            for (int j = 0; j < 4; ++j) {
                u32 hl = (E[j] ^ a0[i]) & TMASK;
                u32 hh = (E[j] ^ b0) & TMASK;
                fv[i][2 * j + 0] = Wl[hl];
                fv[i][2 * j + 1] = Wl[hh];
            }
        }
    }

    #pragma unroll
    for (int i = 0; i < NPT; ++i) {
        float ax = 0.f, ay = 0.f;
        #pragma unroll
        for (int v = 0; v < 8; ++v) {
            float wx = (v & 1) ? dx[i] : 1.f - dx[i];
            float wy = (v & 2) ? dy[i] : 1.f - dy[i];
            float wz = (v & 4) ? dz[i] : 1.f - dz[i];
            float w = (wx * wy) * wz;
            float2 f = unpack16(fv[i][v]);
            ax = fmaf(f.x, w, ax);
            ay = fmaf(f.y, w, ay);
        }
        __builtin_nontemporal_store(packf2(ax, ay), scl + nn[i]);
    }
}

// Fused kernel for levels 2..15 (level-major block order keeps one-table L2 locality)
__global__ __launch_bounds__(256)
void fused_levels(const float* __restrict__ x, const u32* __restrict__ Wh,
                  const u32x2* __restrict__ Gp, u32* __restrict__ scratch,
                  ScaleArgs sc, int N, int TOT, int BPL)
{
    int li = blockIdx.x / BPL;          // 0..13
    int lvl = li + 2;
    int t = (blockIdx.x - li * BPL) * blockDim.x + threadIdx.x;
    if (t >= TOT) return;
    float scale = sc.s[lvl];
    u32* scl = scratch + (size_t)lvl * (size_t)N;

    switch (lvl) {   // block-uniform
        case 2: dense_body<DD2>(x, Gp + GO2, scl, scale, N, TOT, t); break;
        case 3: dense_body<DD3>(x, Gp + GO3, scl, scale, N, TOT, t); break;
        case 4: dense_body<DD4>(x, Gp + GO4, scl, scale, N, TOT, t); break;
        case 5: dense_body<DD5>(x, Gp + GO5, scl, scale, N, TOT, t); break;
        default:
            hash_body(x, Wh + (size_t)(lvl - 6) * TBLN, scl, scale, N, TOT, t);
            break;
    }
}

// LDS-staged transpose: load 256 pts x 16 levels coalesced, emit 1KB-contiguous
// full-line NT stores per wave (no partial-line write amplification).
__global__ __launch_bounds__(256)
void transpose_kernel(const u32* __restrict__ sc, float* __restrict__ out, int N)
{
    __shared__ u32 lds[16][257];
    int P0 = blockIdx.x * 256;
    int t = threadIdx.x;
    #pragma unroll
    for (int l = 0; l < NLEV; ++l) {
        int n = P0 + t;
        if (n < N) lds[l][t] = __builtin_nontemporal_load(sc + (size_t)l * N + n);
    }
    __syncthreads();
    int w = t >> 6, l6 = t & 63;
    #pragma unroll
    for (int k = 0; k < 8; ++k) {
        int p = w * 64 + k * 8 + (l6 >> 3);
        int c = l6 & 7;                       // chunk covers levels 2c, 2c+1
        if (P0 + p < N) {
            float2 f0 = unpack16(lds[2 * c][p]);
            float2 f1 = unpack16(lds[2 * c + 1][p]);
            f32x4 v = { f0.x, f0.y, f1.x, f1.y };
            __builtin_nontemporal_store(v,
                reinterpret_cast<f32x4*>(out + (size_t)(P0 + p) * 32u + (size_t)c * 4u));
        }
    }
}

// ---------------- fallback (round-1 kernel, known-good, f32 exact) ----------
__global__ __launch_bounds__(256)
void hashenc_fallback(const float* __restrict__ x, const float* __restrict__ W,
                      float* __restrict__ out, ScaleArgs sc, int N)
{
    int n = blockIdx.x * blockDim.x + threadIdx.x;
    if (n >= N) return;
    float px = x[(size_t)n * 3 + 0];
    float py = x[(size_t)n * 3 + 1];
    float pz = x[(size_t)n * 3 + 2];
    float acc[2 * NLEV];
    #pragma unroll
    for (int l = 0; l < NLEV; ++l) {
        float s = sc.s[l];
        float ux = px * s, uy = py * s, uz = pz * s;
        int ix = (int)ux, iy = (int)uy, iz = (int)uz;
        float dx = ux - (float)ix, dy = uy - (float)iy, dz = uz - (float)iz;
        unsigned a0 = (unsigned)ix;
        unsigned a1 = (unsigned)iy * PR1;
        unsigned a2 = (unsigned)iz * PR2;
        unsigned b0 = a0 + 1u, b1 = a1 + PR1, b2 = a2 + PR2;
        const float* Wl = W + (size_t)l * TBLN * 2u;
        float ax = 0.f, ay = 0.f;
        #pragma unroll
        for (int v = 0; v < 8; ++v) {
            unsigned h = ((v & 1) ? b0 : a0) ^ ((v & 2) ? b1 : a1) ^ ((v & 4) ? b2 : a2);
            h &= TMASK;
            float wx = (v & 1) ? dx : 1.f - dx;
            float wy = (v & 2) ? dy : 1.f - dy;
            float wz = (v & 4) ? dz : 1.f - dz;
            float w = (wx * wy) * wz;
            const float2 fvv = *reinterpret_cast<const float2*>(Wl + (size_t)h * 2u);
            ax = fmaf(fvv.x, w, ax);
            ay = fmaf(fvv.y, w, ay);
        }
        acc[2 * l + 0] = ax;
        acc[2 * l + 1] = ay;
    }
    float4* o = reinterpret_cast<float4*>(out + (size_t)n * (2 * NLEV));
    #pragma unroll
    for (int j = 0; j < 8; ++j)
        o[j] = make_float4(acc[4 * j + 0], acc[4 * j + 1], acc[4 * j + 2], acc[4 * j + 3]);
}

extern "C" void kernel_launch(void* const* d_in, const int* in_sizes, int n_in,
                              void* d_out, int out_size, void* d_ws, size_t ws_size,
                              hipStream_t stream) {
    const float* x = (const float*)d_in[0];
    const float* W = (const float*)d_in[1];
    float* out = (float*)d_out;
    int N = in_sizes[0] / 3;

    // numpy-exact scales
    ScaleArgs sc;
    double b = exp((log(2048.0) - log(16.0)) / 16.0);
    for (int l = 0; l < NLEV; ++l) {
        double p;
        switch (l) {
            case 0: p = 1.0; break;
            case 1: p = b;   break;
            case 2: p = b * b; break;
            default: p = pow(b, (double)l); break;
        }
        sc.s[l] = (float)(16.0 * p);
    }

    // workspace layout (u32 units): [Wh 10 tables][Gp paired 2..5][Gu 0,1][scratch]
    size_t wh_u32 = (size_t)(NLEV - 6) * TBLN;        // 21.0 MB
    size_t gp_u32 = (size_t)GPTOT * 2u;               // 5.4 MB
    size_t gu_u32 = (size_t)GUTOT;                    // 72 KB
    size_t scr_u32 = (size_t)NLEV * (size_t)N;        // 128 MB
    size_t need = (wh_u32 + gp_u32 + gu_u32 + scr_u32) * sizeof(u32);  // ~154.5 MB

    if (ws_size >= need) {
        u32* Wh = (u32*)d_ws;
        u32x2* Gp = reinterpret_cast<u32x2*>(Wh + wh_u32);
        u32* Gu = Wh + wh_u32 + gp_u32;
        u32* scratch = Gu + gu_u32;

        // fp16 tables for hash levels 6..15
        int np4 = (int)(wh_u32 / 4);
        hipLaunchKernelGGL(convert_w, dim3((np4 + 255) / 256), dim3(256), 0, stream,
                           W + (size_t)6 * TBLN * 2u, Wh, np4);

        // unpaired LDS grids for levels 0,1
        {
            int P0c = DU0 * DU0 * DU0;
            hipLaunchKernelGGL(build_unpaired, dim3((P0c + 255) / 256), dim3(256), 0, stream,
                               W + 0, Gu + GU0, DU0, P0c);
            int P1c = DU1 * DU1 * DU1;
            hipLaunchKernelGGL(build_unpaired, dim3((P1c + 255) / 256), dim3(256), 0, stream,
                               W + (size_t)1 * TBLN * 2u, Gu + GU1, DU1, P1c);
        }

        // paired grids for levels 2..5
        const int Dl[4] = { DD2, DD3, DD4, DD5 };
        const int Ol[4] = { GO2, GO3, GO4, GO5 };
        for (int i = 0; i < 4; ++i) {
            int l = 2 + i;
            int P = (Dl[i] - 1) * Dl[i] * Dl[i];
            hipLaunchKernelGGL(build_dense, dim3((P + 255) / 256), dim3(256), 0, stream,
                               W + (size_t)l * TBLN * 2u, Gp + Ol[i], Dl[i], P);
        }

        // levels 0,1 via LDS-resident grids (zero L2 gather slots)
        {
            int blocks = (N + 256 * NPTL - 1) / (256 * NPTL);
            hipLaunchKernelGGL(lds_level<DU0>, dim3(blocks), dim3(256), 0, stream,
                               x, Gu + GU0, scratch + 0, sc.s[0], N);
            hipLaunchKernelGGL(lds_level<DU1>, dim3(blocks), dim3(256), 0, stream,
                               x, Gu + GU1, scratch + (size_t)N, sc.s[1], N);
        }

        // levels 2..15 fused (level-major)
        int TOT = (N + NPT - 1) / NPT;
        int BPL = (TOT + 255) / 256;
        hipLaunchKernelGGL(fused_levels, dim3(14 * BPL), dim3(256), 0, stream,
                           x, Wh, Gp, scratch, sc, N, TOT, BPL);

        int gt = (N + 255) / 256;
        hipLaunchKernelGGL(transpose_kernel, dim3(gt), dim3(256), 0, stream,
                           scratch, out, N);
    } else {
        int grid = (N + 255) / 256;
        hipLaunchKernelGGL(hashenc_fallback, dim3(grid), dim3(256), 0, stream,
                           x, W, out, sc, N);
    }
}